// Round 1
// baseline (244.100 us; speedup 1.0000x reference)
//
#include <hip/hip_runtime.h>
#include <hip/hip_bf16.h>
#include <stdint.h>

// KAN-like regressor: N=65536 rows, D=32 features, H=128.
// out[n] = sum_d ( relu( relu(x[n,d]*W1[d,:]+b1[d,:]) @ W2[d] ) . W3[d] + b3[d] )
// Strategy: one block per (feature d, block-slot); W2[d] bf16 B-fragments held in
// REGISTERS (persistent across row tiles); h1 computed on the fly into LDS A-frags;
// mfma_f32_16x16x32_bf16; epilogue folds b2/relu/W3-dot + shfl butterfly reduce;
// fp32 atomicAdd into out (init kernel pre-fills out with sum_d b3[d]).

#define D_FEAT 32
#define H_DIM  128
#define BM     64          // rows per tile
#define BLOCKS_PER_D 32
#define THREADS 256        // 4 waves

typedef float f32x4 __attribute__((ext_vector_type(4)));
typedef short bf16x8 __attribute__((ext_vector_type(8)));

static __device__ __forceinline__ short f2bf(float f) {
    uint32_t u = __builtin_bit_cast(uint32_t, f);
    uint32_t r = (u + 0x7FFFu + ((u >> 16) & 1u)) >> 16;   // RNE
    return (short)(r & 0xFFFFu);
}
static __device__ __forceinline__ int packbf2(float a, float b) {
    return (int)((uint32_t)(uint16_t)f2bf(a) | ((uint32_t)(uint16_t)f2bf(b) << 16));
}

__global__ __launch_bounds__(256) void kan_init_out(const float* __restrict__ b3,
                                                    float* __restrict__ out, int n) {
    int i = blockIdx.x * blockDim.x + threadIdx.x;
    float s = 0.f;
#pragma unroll
    for (int d = 0; d < D_FEAT; ++d) s += b3[d];
    if (i < n) out[i] = s;
}

__global__ __launch_bounds__(THREADS) void kan_main(
    const float* __restrict__ x,    // [N, 32]
    const float* __restrict__ W1,   // [32, 128]
    const float* __restrict__ b1,   // [32, 128]
    const float* __restrict__ W2,   // [32, 128, 128]
    const float* __restrict__ b2,   // [32, 128]
    const float* __restrict__ W3,   // [32, 128]
    float* __restrict__ out,        // [N]
    int N)
{
    __shared__ int4  aFragV[4 * 4 * 64];     // 16 KB: A frags, combo f=(mt*4+s)*64+l
    __shared__ float xbuf[BM];
    __shared__ float W1s[H_DIM], b1s[H_DIM], b2s[H_DIM], W3s[H_DIM];
    __shared__ float rowbuf[4][BM];          // per-wave partial row sums

    const int tid  = threadIdx.x;
    const int d    = blockIdx.x / BLOCKS_PER_D;
    const int bslot= blockIdx.x % BLOCKS_PER_D;
    const int w    = tid >> 6;   // wave 0..3
    const int l    = tid & 63;   // lane
    const int l15  = l & 15;
    const int q    = l >> 4;     // quadrant 0..3

    // ---- per-feature params -> LDS ----
    if (tid < H_DIM) {
        W1s[tid] = W1[d * H_DIM + tid];
        b1s[tid] = b1[d * H_DIM + tid];
        b2s[tid] = b2[d * H_DIM + tid];
        W3s[tid] = W3[d * H_DIM + tid];
    }

    // ---- stage W2[d] as bf16 B-fragments in registers ----
    // wave w owns N-tiles {2w, 2w+1}. For (nt,s,lane l,elem j):
    //   k = 32*s + 4*q + (j&3) + 16*(j>>2),  n = 16*t + l15   (same k-map as A)
    bf16x8 bfrag[2][4];
    {
        const float* W2d = W2 + (size_t)d * H_DIM * H_DIM;
#pragma unroll
        for (int nt = 0; nt < 2; ++nt) {
            int t = 2 * w + nt;
#pragma unroll
            for (int s = 0; s < 4; ++s) {
                bf16x8 bf;
#pragma unroll
                for (int j = 0; j < 8; ++j) {
                    int k = 32 * s + 4 * q + (j & 3) + 16 * (j >> 2);
                    int n = 16 * t + l15;
                    bf[j] = f2bf(W2d[k * H_DIM + n]);
                }
                bfrag[nt][s] = bf;
            }
        }
    }
    __syncthreads();

    const int ntiles = N / BM;
    for (int tile = bslot; tile < ntiles; tile += BLOCKS_PER_D) {
        const int n0 = tile * BM;

        // (a0) load x column d for this tile
        if (tid < BM) xbuf[tid] = x[(size_t)(n0 + tid) * D_FEAT + d];
        __syncthreads();

        // (a2) h1 = relu(x*W1+b1) -> bf16 A-fragments in LDS
#pragma unroll
        for (int c = 0; c < 4; ++c) {
            int f  = tid + 256 * c;          // 0..1023
            int mt = f >> 8;
            int s  = (f >> 6) & 3;
            int ll = f & 63;
            int r  = 16 * mt + (ll & 15);
            int hb = 32 * s + 4 * ((ll >> 4) & 3);
            float xv = xbuf[r];
            const float4 w1a = *reinterpret_cast<const float4*>(&W1s[hb]);
            const float4 w1b = *reinterpret_cast<const float4*>(&W1s[hb + 16]);
            const float4 b1a = *reinterpret_cast<const float4*>(&b1s[hb]);
            const float4 b1b = *reinterpret_cast<const float4*>(&b1s[hb + 16]);
            float v0 = fmaxf(xv * w1a.x + b1a.x, 0.f);
            float v1 = fmaxf(xv * w1a.y + b1a.y, 0.f);
            float v2 = fmaxf(xv * w1a.z + b1a.z, 0.f);
            float v3 = fmaxf(xv * w1a.w + b1a.w, 0.f);
            float v4 = fmaxf(xv * w1b.x + b1b.x, 0.f);
            float v5 = fmaxf(xv * w1b.y + b1b.y, 0.f);
            float v6 = fmaxf(xv * w1b.z + b1b.z, 0.f);
            float v7 = fmaxf(xv * w1b.w + b1b.w, 0.f);
            int4 pk;
            pk.x = packbf2(v0, v1);
            pk.y = packbf2(v2, v3);
            pk.z = packbf2(v4, v5);
            pk.w = packbf2(v6, v7);
            aFragV[f] = pk;
        }
        __syncthreads();

        // (c) GEMM: rows 0..63 x cols (wave's 32) over K=128
        f32x4 acc[4][2];
#pragma unroll
        for (int mt = 0; mt < 4; ++mt)
#pragma unroll
            for (int nt = 0; nt < 2; ++nt)
                acc[mt][nt] = (f32x4){0.f, 0.f, 0.f, 0.f};

#pragma unroll
        for (int mt = 0; mt < 4; ++mt) {
#pragma unroll
            for (int s = 0; s < 4; ++s) {
                bf16x8 a = *reinterpret_cast<const bf16x8*>(&aFragV[(mt * 4 + s) * 64 + l]);
#pragma unroll
                for (int nt = 0; nt < 2; ++nt) {
                    acc[mt][nt] = __builtin_amdgcn_mfma_f32_16x16x32_bf16(
                        a, bfrag[nt][s], acc[mt][nt], 0, 0, 0);
                }
            }
        }

        // epilogue: relu(acc+b2)*W3, sum over this wave's 32 cols
        float rp[4][4];
#pragma unroll
        for (int mt = 0; mt < 4; ++mt) {
#pragma unroll
            for (int i = 0; i < 4; ++i) {
                float sum = 0.f;
#pragma unroll
                for (int nt = 0; nt < 2; ++nt) {
                    int cidx = 16 * (2 * w + nt) + l15;
                    float v = acc[mt][nt][i] + b2s[cidx];
                    v = fmaxf(v, 0.f);
                    sum += v * W3s[cidx];
                }
                rp[mt][i] = sum;
            }
        }
        // butterfly reduce across the 16 lanes of each quadrant group
#pragma unroll
        for (int mask = 1; mask < 16; mask <<= 1)
#pragma unroll
            for (int mt = 0; mt < 4; ++mt)
#pragma unroll
                for (int i = 0; i < 4; ++i)
                    rp[mt][i] += __shfl_xor(rp[mt][i], mask, 64);

        if (l15 == 0) {
#pragma unroll
            for (int mt = 0; mt < 4; ++mt)
#pragma unroll
                for (int i = 0; i < 4; ++i)
                    rowbuf[w][16 * mt + 4 * q + i] = rp[mt][i];
        }
        __syncthreads();

        // (e) combine 4 waves, one atomic per row
        if (tid < BM) {
            float s4 = rowbuf[0][tid] + rowbuf[1][tid] + rowbuf[2][tid] + rowbuf[3][tid];
            atomicAdd(&out[n0 + tid], s4);
        }
    }
}

extern "C" void kernel_launch(void* const* d_in, const int* in_sizes, int n_in,
                              void* d_out, int out_size, void* d_ws, size_t ws_size,
                              hipStream_t stream) {
    const float* x  = (const float*)d_in[0];
    const float* W1 = (const float*)d_in[1];
    const float* b1 = (const float*)d_in[2];
    const float* W2 = (const float*)d_in[3];
    const float* b2 = (const float*)d_in[4];
    const float* W3 = (const float*)d_in[5];
    const float* b3 = (const float*)d_in[6];
    float* out = (float*)d_out;
    const int N = in_sizes[0] / D_FEAT;   // 65536

    kan_init_out<<<(N + 255) / 256, 256, 0, stream>>>(b3, out, N);
    kan_main<<<D_FEAT * BLOCKS_PER_D, THREADS, 0, stream>>>(x, W1, b1, W2, b2, W3, out, N);
}

// Round 2
// 198.588 us; speedup vs baseline: 1.2292x; 1.2292x over previous
//
#include <hip/hip_runtime.h>
#include <hip/hip_bf16.h>
#include <stdint.h>

// KAN-like regressor: N=65536, D=32 features, H=128.
// out[n] = sum_d ( relu( relu(x[n,d]*W1[d,:]+b1[d,:]) @ W2[d] ) . W3[d] + b3[d] )
//
// Design R (round 2): transposed GEMM h2^T = W2^T x h1^T with 32x32x16 bf16 MFMA.
//  - h1 computed BY MFMA (K=2 rank-2 GEMM: [W1|b1] x [x;1]) -> D1 regs
//  - D1 reg layout bijects onto B-fragment k-map (r = e + 8s): relu + v_cvt_pk_bf16_f32
//    turns D1 directly into main-GEMM B-frags IN REGISTERS. No LDS staging, no barriers.
//  - 4 waves split M (h_out 32 each); W2^T frags persistent in 32 VGPR/wave.
//  - Epilogue: W3-dot is lane-local (D col = row n = lane&31), one shfl_xor(32),
//    one global atomicAdd per wave-tile.

#define D_FEAT 32
#define H_DIM  128
#define BM     64
#define SLOTS  32          // blocks per feature; grid = 32*32 = 1024
#define TILES  32          // N / BM / SLOTS
#define THREADS 256        // 4 waves

typedef float    f32x16 __attribute__((ext_vector_type(16)));
typedef short    bf16x8 __attribute__((ext_vector_type(8)));
typedef uint32_t u32;

static __device__ __forceinline__ u32 f2bf(float f) {      // RNE, cold path only
    u32 u = __builtin_bit_cast(u32, f);
    return ((u + 0x7FFFu + ((u >> 16) & 1u)) >> 16) & 0xFFFFu;
}
static __device__ __forceinline__ u32 pk_cold(float lo, float hi) {
    return f2bf(lo) | (f2bf(hi) << 16);
}
static __device__ __forceinline__ u32 cvtpk(float lo, float hi) {  // hot: 1 VALU op
    u32 r;
    asm("v_cvt_pk_bf16_f32 %0, %1, %2" : "=v"(r) : "v"(lo), "v"(hi));
    return r;
}
static __device__ __forceinline__ bf16x8 frag4(u32 a, u32 b, u32 c, u32 d) {
    int4 t = make_int4((int)a, (int)b, (int)c, (int)d);
    return __builtin_bit_cast(bf16x8, t);
}

__global__ __launch_bounds__(256) void kan_init_out(const float* __restrict__ b3,
                                                    float* __restrict__ out, int n) {
    int i = blockIdx.x * blockDim.x + threadIdx.x;
    float s = 0.f;
#pragma unroll
    for (int k = 0; k < D_FEAT; ++k) s += b3[k];   // uniform -> scalar loads
    if (i < n) out[i] = s;
}

__global__ __launch_bounds__(THREADS, 3) void kan_main(
    const float* __restrict__ x,    // [N, 32]
    const float* __restrict__ W1,   // [32, 128]
    const float* __restrict__ b1,   // [32, 128]
    const float* __restrict__ W2,   // [32, 128, 128]  (h_in, h_out) per d
    const float* __restrict__ b2,   // [32, 128]
    const float* __restrict__ W3,   // [32, 128]
    float* __restrict__ out,        // [N]
    int N)
{
    __shared__ float xall[TILES * BM];     // 8 KB: all x rows this block will touch
    __shared__ float b2s[H_DIM], W3s[H_DIM];

    const int tid   = threadIdx.x;
    const int d     = blockIdx.x / SLOTS;
    const int bslot = blockIdx.x % SLOTS;
    const int w     = tid >> 6;            // wave 0..3 -> h_out chunk [32w, 32w+32)
    const int l     = tid & 63;
    const int l31   = l & 31;
    const int g     = l >> 5;              // lane group 0/1

    if (tid < H_DIM) {
        b2s[tid] = b2[d * H_DIM + tid];
        W3s[tid] = W3[d * H_DIM + tid];
    }
    // preload every x value this block needs (tiles are bslot + 32*t)
#pragma unroll
    for (int i = 0; i < (TILES * BM) / THREADS; ++i) {
        int idx = tid + THREADS * i;               // 0..2047
        int tl  = idx >> 6, r = idx & 63;
        xall[idx] = x[(size_t)((bslot + SLOTS * tl) * BM + r) * D_FEAT + d];
    }

    // per-lane packed (W1[m], b1[m]) for h1-MFMA A operand; only g==0 lanes carry k=0,1
    u32 w1b1[4];
#pragma unroll
    for (int mt = 0; mt < 4; ++mt) {
        int m = 32 * mt + l31;
        u32 v = pk_cold(W1[d * H_DIM + m], b1[d * H_DIM + m]);
        w1b1[mt] = (g == 0) ? v : 0u;
    }

    // W2^T A-fragments, persistent: lane holds m = 32w + l31; elem e -> k = 16ks+4g+(e&3)+8(e>>2)
    bf16x8 w2f[8];
    {
        const float* W2d = W2 + (size_t)d * H_DIM * H_DIM;
        const int m = 32 * w + l31;
#pragma unroll
        for (int ks = 0; ks < 8; ++ks) {
            u32 dw[4];
#pragma unroll
            for (int p = 0; p < 4; ++p) {
                int e0 = 2 * p, e1 = 2 * p + 1;
                int k0 = 16 * ks + 4 * g + (e0 & 3) + 8 * (e0 >> 2);
                int k1 = 16 * ks + 4 * g + (e1 & 3) + 8 * (e1 >> 2);
                dw[p] = pk_cold(W2d[(size_t)k0 * H_DIM + m], W2d[(size_t)k1 * H_DIM + m]);
            }
            w2f[ks] = frag4(dw[0], dw[1], dw[2], dw[3]);
        }
    }
    __syncthreads();   // the ONLY barrier

    const f32x16 zc = {};

    for (int t = 0; t < TILES; ++t) {
        const int base = t * BM;
        f32x16 acc[2];
        acc[0] = zc; acc[1] = zc;

#pragma unroll
        for (int mt = 0; mt < 4; ++mt) {          // h1 h-tile = main-GEMM k-tile pair
#pragma unroll
            for (int nt = 0; nt < 2; ++nt) {      // 32-row chunk
                // B operand of h1-MFMA: k=0 -> x[n], k=1 -> 1.0 (g==0 lanes only)
                float xv = xall[base + 32 * nt + l31];
                u32 xp = (g == 0) ? (cvtpk(xv, 1.0f)) : 0u;
                bf16x8 Ah = frag4(w1b1[mt], 0u, 0u, 0u);
                bf16x8 Bx = frag4(xp, 0u, 0u, 0u);
                // D1[h=32*mt+rho(g,r), n=32*nt+l31] = x*W1 + b1
                f32x16 d1 = __builtin_amdgcn_mfma_f32_32x32x16_bf16(Ah, Bx, zc, 0, 0, 0);
#pragma unroll
                for (int s = 0; s < 2; ++s) {     // split 16 regs into 2 K-steps
                    // relu + pack: D1 reg r = e + 8s feeds B elem e of k-step 2mt+s
                    u32 c0 = cvtpk(fmaxf(d1[8 * s + 0], 0.f), fmaxf(d1[8 * s + 1], 0.f));
                    u32 c1 = cvtpk(fmaxf(d1[8 * s + 2], 0.f), fmaxf(d1[8 * s + 3], 0.f));
                    u32 c2 = cvtpk(fmaxf(d1[8 * s + 4], 0.f), fmaxf(d1[8 * s + 5], 0.f));
                    u32 c3 = cvtpk(fmaxf(d1[8 * s + 6], 0.f), fmaxf(d1[8 * s + 7], 0.f));
                    bf16x8 Bm = frag4(c0, c1, c2, c3);
                    acc[nt] = __builtin_amdgcn_mfma_f32_32x32x16_bf16(
                        w2f[2 * mt + s], Bm, acc[nt], 0, 0, 0);
                }
            }
        }

        // epilogue: rs[nt] = sum over wave's 32 h_out of relu(acc+b2)*W3 (lane-local rows)
        float4 b2a[4], w3a[4];
#pragma unroll
        for (int q4 = 0; q4 < 4; ++q4) {
            b2a[q4] = *reinterpret_cast<const float4*>(&b2s[32 * w + 4 * g + 8 * q4]);
            w3a[q4] = *reinterpret_cast<const float4*>(&W3s[32 * w + 4 * g + 8 * q4]);
        }
        float rs0 = 0.f, rs1 = 0.f;
#pragma unroll
        for (int r = 0; r < 16; ++r) {
            float bb = ((const float*)&b2a[r >> 2])[r & 3];
            float ww = ((const float*)&w3a[r >> 2])[r & 3];
            rs0 += fmaxf(acc[0][r] + bb, 0.f) * ww;
            rs1 += fmaxf(acc[1][r] + bb, 0.f) * ww;
        }
        // reduce over lane-group g (h_out +4g): partner lane l^32 has same row n
        rs0 += __shfl_xor(rs0, 32, 64);
        rs1 += __shfl_xor(rs1, 32, 64);
        float val = (l < 32) ? rs0 : rs1;         // lane l owns row base + l
        atomicAdd(&out[(size_t)(bslot + SLOTS * t) * BM + l], val);
    }
}

extern "C" void kernel_launch(void* const* d_in, const int* in_sizes, int n_in,
                              void* d_out, int out_size, void* d_ws, size_t ws_size,
                              hipStream_t stream) {
    const float* x  = (const float*)d_in[0];
    const float* W1 = (const float*)d_in[1];
    const float* b1 = (const float*)d_in[2];
    const float* W2 = (const float*)d_in[3];
    const float* b2 = (const float*)d_in[4];
    const float* W3 = (const float*)d_in[5];
    const float* b3 = (const float*)d_in[6];
    float* out = (float*)d_out;
    const int N = in_sizes[0] / D_FEAT;   // 65536

    kan_init_out<<<(N + 255) / 256, 256, 0, stream>>>(b3, out, N);
    kan_main<<<D_FEAT * SLOTS, THREADS, 0, stream>>>(x, W1, b1, W2, b2, W3, out, N);
}

// Round 3
// 157.117 us; speedup vs baseline: 1.5536x; 1.2640x over previous
//
#include <hip/hip_runtime.h>
#include <hip/hip_bf16.h>
#include <stdint.h>

// KAN-like regressor: N=65536, D=32 features, H=128.
// out[n] = sum_d ( relu( relu(x[n,d]*W1[d,:]+b1[d,:]) @ W2[d] ) . W3[d] + b3[d] )
//
// R3: N-split waves (each wave owns 32 rows/iter, all 128 h_out).
//  - W2^T A-frags persistent in 128 VGPR/lane (all waves identical set).
//  - h1 via K=2 MFMA ([W1|b1]x[x;1]); D1 regs -> B-frags via r=e+8s bijection
//    (relu+v_cvt_pk_bf16_f32), verified in R1/R2.
//  - b2 folded as rank-1 MFMA (b2 * ones^T) seeding the acc chains.
//  - W3-dot as MFMA: relu(h2) D-regs -> B-frags (same bijection), A = W3
//    broadcast frags from LDS (2-way broadcast reads, conflict-free).
//  - No barriers in loop, 1 atomicAdd per row, no shfl.
//  - __launch_bounds__(256,2): 256-VGPR budget -> pure VGPR, no accvgpr churn.

#define D_FEAT 32
#define H_DIM  128
#define SLOTS  16
#define THREADS 256        // 4 waves
#define RPB    4096        // rows per block = N / SLOTS
#define ITERS  32          // RPB / 128

typedef float    f32x16 __attribute__((ext_vector_type(16)));
typedef short    bf16x8 __attribute__((ext_vector_type(8)));
typedef uint32_t u32;

static __device__ __forceinline__ u32 cvtpk(float lo, float hi) {
    u32 r;
    asm("v_cvt_pk_bf16_f32 %0, %1, %2" : "=v"(r) : "v"(lo), "v"(hi));
    return r;
}
static __device__ __forceinline__ bf16x8 frag4(u32 a, u32 b, u32 c, u32 d) {
    int4 t = make_int4((int)a, (int)b, (int)c, (int)d);
    return __builtin_bit_cast(bf16x8, t);
}
static __device__ __forceinline__ bf16x8 frag1(u32 a) { return frag4(a, 0u, 0u, 0u); }

#define MFMA32(A, B, C) __builtin_amdgcn_mfma_f32_32x32x16_bf16((A), (B), (C), 0, 0, 0)

// relu + pack 8 consecutive D-regs (half s) into one B-frag; s must be unroll-const.
static __device__ __forceinline__ bf16x8 relu_pack(const f32x16& v, int s) {
    u32 c0 = cvtpk(fmaxf(v[8*s+0], 0.f), fmaxf(v[8*s+1], 0.f));
    u32 c1 = cvtpk(fmaxf(v[8*s+2], 0.f), fmaxf(v[8*s+3], 0.f));
    u32 c2 = cvtpk(fmaxf(v[8*s+4], 0.f), fmaxf(v[8*s+5], 0.f));
    u32 c3 = cvtpk(fmaxf(v[8*s+6], 0.f), fmaxf(v[8*s+7], 0.f));
    return frag4(c0, c1, c2, c3);
}

__global__ __launch_bounds__(256) void kan_init_out(const float* __restrict__ b3,
                                                    float* __restrict__ out, int n) {
    int i = blockIdx.x * blockDim.x + threadIdx.x;
    float s = 0.f;
#pragma unroll
    for (int k = 0; k < D_FEAT; ++k) s += b3[k];
    if (i < n) out[i] = s;
}

__global__ __launch_bounds__(THREADS, 2) void kan_main(
    const float* __restrict__ x,    // [N, 32]
    const float* __restrict__ W1,   // [32, 128]
    const float* __restrict__ b1,   // [32, 128]
    const float* __restrict__ W2,   // [32, 128, 128]  (h_in, h_out) per d
    const float* __restrict__ b2,   // [32, 128]
    const float* __restrict__ W3,   // [32, 128]
    float* __restrict__ out)        // [N]
{
    __shared__ float xall[RPB];        // 16 KB
    __shared__ u32 w3lds[2][8][4];     // 256 B: W3 A-frags per (group, ks2)

    const int tid   = threadIdx.x;
    const int d     = blockIdx.x / SLOTS;
    const int bslot = blockIdx.x % SLOTS;
    const int w     = tid >> 6;
    const int l     = tid & 63;
    const int l31   = l & 31;
    const int g     = l >> 5;
    const size_t rowbase = (size_t)bslot * RPB;

    // preload this block's x column
#pragma unroll
    for (int i = 0; i < RPB / THREADS; ++i) {
        int idx = tid + THREADS * i;
        xall[idx] = x[(rowbase + idx) * D_FEAT + d];
    }
    // W3 broadcast A-frags: value = W3[k2], identical for every A-row.
    if (tid < 16) {
        int gg = tid >> 3, ks2 = tid & 7;
        const float* W3d = W3 + d * H_DIM;
#pragma unroll
        for (int p = 0; p < 4; ++p) {
            int e0 = 2 * p, e1 = 2 * p + 1;
            int k0 = 16 * ks2 + 4 * gg + (e0 & 3) + 8 * (e0 >> 2);
            int k1 = 16 * ks2 + 4 * gg + (e1 & 3) + 8 * (e1 >> 2);
            w3lds[gg][ks2][p] = cvtpk(W3d[k0], W3d[k1]);
        }
    }

    // per-lane cold fragments: (W1,b1) pairs and b2 (k=0 slot, group 0 only)
    u32 w1b1[4], b2w[4];
#pragma unroll
    for (int mt = 0; mt < 4; ++mt) {
        int m = 32 * mt + l31;
        u32 v  = cvtpk(W1[d * H_DIM + m], b1[d * H_DIM + m]);
        u32 bb = cvtpk(b2[d * H_DIM + m], 0.0f);
        w1b1[mt] = g ? 0u : v;
        b2w[mt]  = g ? 0u : bb;
    }
    const u32 onesw = g ? 0u : 0x00003F80u;   // bf16(1.0) at k=0

    // W2^T A-frags, persistent 128 VGPR: lane m = 32*mo + l31,
    // elem e -> k = 16*ks + 4*g + (e&3) + 8*(e>>2)
    bf16x8 w2f[4][8];
    {
        const float* W2d = W2 + (size_t)d * H_DIM * H_DIM;
#pragma unroll
        for (int mo = 0; mo < 4; ++mo) {
            int mm = 32 * mo + l31;
#pragma unroll
            for (int ks = 0; ks < 8; ++ks) {
                u32 dw[4];
#pragma unroll
                for (int p = 0; p < 4; ++p) {
                    int e0 = 2 * p, e1 = 2 * p + 1;
                    int k0 = 16 * ks + 4 * g + (e0 & 3) + 8 * (e0 >> 2);
                    int k1 = 16 * ks + 4 * g + (e1 & 3) + 8 * (e1 >> 2);
                    dw[p] = cvtpk(W2d[(size_t)k0 * H_DIM + mm],
                                  W2d[(size_t)k1 * H_DIM + mm]);
                }
                w2f[mo][ks] = frag4(dw[0], dw[1], dw[2], dw[3]);
            }
        }
    }
    __syncthreads();   // the only barrier

    const f32x16 zc = {};

    for (int t = 0; t < ITERS; ++t) {
        const int loff = t * 128 + 32 * w;          // wave's 32-row chunk
        float xv = xall[loff + l31];
        u32 xpk = g ? 0u : cvtpk(xv, 1.0f);
        bf16x8 Bx = frag1(xpk);

        // h1 for this wave's rows -> 8 B-frags (full K=128)
        bf16x8 bfr[8];
#pragma unroll
        for (int mt = 0; mt < 4; ++mt) {
            f32x16 d1 = MFMA32(frag1(w1b1[mt]), Bx, zc);
            bfr[2 * mt + 0] = relu_pack(d1, 0);
            bfr[2 * mt + 1] = relu_pack(d1, 1);
        }

        // main GEMM (M=128 split in 2 passes of 2 chains) + fused epilogue
        f32x16 acc2 = zc;
        const bf16x8 onesB = frag1(onesw);
#pragma unroll
        for (int pa = 0; pa < 2; ++pa) {
            // seed with b2 (rank-1 MFMA: D = b2[m] * 1)
            f32x16 a0 = MFMA32(frag1(b2w[2 * pa + 0]), onesB, zc);
            f32x16 a1 = MFMA32(frag1(b2w[2 * pa + 1]), onesB, zc);
#pragma unroll
            for (int ks = 0; ks < 8; ++ks) {
                a0 = MFMA32(w2f[2 * pa + 0][ks], bfr[ks], a0);
                a1 = MFMA32(w2f[2 * pa + 1][ks], bfr[ks], a1);
            }
            // W3-dot: relu(h2) regs -> B-frags (same r=e+8s bijection),
            // A = W3 broadcast frag from LDS (2-way broadcast read)
            {
                const int mo0 = 2 * pa + 0, mo1 = 2 * pa + 1;
                bf16x8 w3a, w3b, w3c, w3d;
                w3a = *reinterpret_cast<const bf16x8*>(&w3lds[g][2 * mo0 + 0][0]);
                w3b = *reinterpret_cast<const bf16x8*>(&w3lds[g][2 * mo0 + 1][0]);
                w3c = *reinterpret_cast<const bf16x8*>(&w3lds[g][2 * mo1 + 0][0]);
                w3d = *reinterpret_cast<const bf16x8*>(&w3lds[g][2 * mo1 + 1][0]);
                acc2 = MFMA32(w3a, relu_pack(a0, 0), acc2);
                acc2 = MFMA32(w3b, relu_pack(a0, 1), acc2);
                acc2 = MFMA32(w3c, relu_pack(a1, 0), acc2);
                acc2 = MFMA32(w3d, relu_pack(a1, 1), acc2);
            }
        }
        // every row p of acc2 holds the full 128-h dot for n = l31
        if (!g) atomicAdd(&out[rowbase + loff + l31], acc2[0]);
    }
}

extern "C" void kernel_launch(void* const* d_in, const int* in_sizes, int n_in,
                              void* d_out, int out_size, void* d_ws, size_t ws_size,
                              hipStream_t stream) {
    const float* x  = (const float*)d_in[0];
    const float* W1 = (const float*)d_in[1];
    const float* b1 = (const float*)d_in[2];
    const float* W2 = (const float*)d_in[3];
    const float* b2 = (const float*)d_in[4];
    const float* W3 = (const float*)d_in[5];
    const float* b3 = (const float*)d_in[6];
    float* out = (float*)d_out;
    const int N = in_sizes[0] / D_FEAT;   // 65536

    kan_init_out<<<(N + 255) / 256, 256, 0, stream>>>(b3, out, N);
    kan_main<<<D_FEAT * SLOTS, THREADS, 0, stream>>>(x, W1, b1, W2, b2, W3, out);
}